// Round 7
// baseline (12232.001 us; speedup 1.0000x reference)
//
#include <hip/hip_runtime.h>
#include <hip/hip_bf16.h>
#include <hip/hip_fp16.h>

constexpr int kNodes = 50000;
constexpr int kNE    = 800000;            // edges before self loops
constexpr int kET    = 850000;            // kNE + kNodes self loops
constexpr int kFin   = 256;
constexpr int kC     = 32;
constexpr int kH     = 4;
constexpr int kHC    = 128;               // kH * kC
constexpr float kEps   = 1e-5f;
constexpr float kSlope = 0.2f;
constexpr float kShift = 8.0f;            // global logit shift (softmax-invariant)

// ---- zero-fill (graph-capture-safe replacement for hipMemsetAsync)
__global__ void __launch_bounds__(256) k_fill0(unsigned* __restrict__ p, int n) {
    int i = blockIdx.x * 256 + threadIdx.x;
    if (i < n) p[i] = 0u;
}

// ---- K1: h0 = relu(node_ln(x @ W_emb + b_emb)); jk = h0.
// block = 256 threads = 8 nodes x 32 channels; LN via LDS.
__global__ void __launch_bounds__(256) k_embed(
    const float* __restrict__ x, const float* __restrict__ W, const float* __restrict__ b,
    const float* __restrict__ lnw, const float* __restrict__ lnb,
    float* __restrict__ h, float* __restrict__ jk) {
    int t = threadIdx.x;
    int ng = t >> 5;               // node within block, 0..7
    int c  = t & 31;
    int node = blockIdx.x * 8 + ng;
    __shared__ float sy[8][33];
    float y = 0.f;
    if (node < kNodes) {
        const float* xp = x + (long)node * kFin;
        float acc = 0.f;
        for (int k = 0; k < kFin; ++k) acc += xp[k] * W[k * kC + c];
        y = acc + b[c];
    }
    sy[ng][c] = y;
    __syncthreads();
    if (node >= kNodes) return;
    float m = 0.f;
    for (int j = 0; j < kC; ++j) m += sy[ng][j];
    m *= (1.f / kC);
    float q = 0.f;
    for (int j = 0; j < kC; ++j) { float d = sy[ng][j] - m; q += d * d; }
    q *= (1.f / kC);
    float out = (y - m) * rsqrtf(q + kEps) * lnw[c] + lnb[c];
    out = fmaxf(out, 0.f);
    h[node * kC + c] = out;
    jk[node * kC + c] = out;
}

// ---- K2: xl = h@Wl + bl (fp16) ; xr = h@Wr + br (fp32). One thread per (node, j).
__global__ void __launch_bounds__(256) k_trans(
    const float* __restrict__ h,
    const float* __restrict__ Wl, const float* __restrict__ bl,
    const float* __restrict__ Wr, const float* __restrict__ br,
    __half* __restrict__ xl, float* __restrict__ xr) {
    int gid = blockIdx.x * 256 + threadIdx.x;
    if (gid >= kNodes * kHC) return;
    int node = gid >> 7, j = gid & 127;
    const float* hp = h + (long)node * kC;
    float al = bl[j], ar = br[j];
    for (int k = 0; k < kC; ++k) {
        float hk = hp[k];
        al += hk * Wl[k * kHC + j];
        ar += hk * Wr[k * kHC + j];
    }
    xl[gid] = __float2half(al);
    xr[gid] = ar;
}

// ---- K3: per (edge, head): ex = exp(logit - kShift); segment-sum into ssum.
__global__ void __launch_bounds__(256) k_logits(
    const int* __restrict__ src, const int* __restrict__ dst, const float* __restrict__ ea,
    const __half* __restrict__ xl, const float* __restrict__ xr,
    const float* __restrict__ We, const float* __restrict__ att,
    __half* __restrict__ exbuf, float* __restrict__ ssum) {
    int gid = blockIdx.x * 256 + threadIdx.x;
    if (gid >= kET * kH) return;
    int e = gid >> 2, hh = gid & 3;
    int si = (e < kNE) ? src[e] : e - kNE;
    int di = (e < kNE) ? dst[e] : e - kNE;
    float eav = (e < kNE) ? ea[e] : 0.f;
    const __half* pl = xl + (long)si * kHC + hh * kC;
    const float*  pr = xr + (long)di * kHC + hh * kC;
    float acc = 0.f;
    for (int c = 0; c < kC; ++c) {
        float z = __half2float(pl[c]) + pr[c] + eav * We[hh * kC + c];
        z = (z > 0.f) ? z : kSlope * z;
        acc += z * att[hh * kC + c];
    }
    float t = fmaxf(acc - kShift, -14.f);          // keep exp within fp16 range
    __half hex = __float2half(expf(t));
    exbuf[gid] = hex;
    atomicAdd(&ssum[di * kH + hh], __half2float(hex));  // sum the rounded value
}

// ---- K4: g[dst] += (ex/ssum[dst]) * xl[src]
__global__ void __launch_bounds__(256) k_scatter(
    const int* __restrict__ src, const int* __restrict__ dst,
    const __half* __restrict__ exbuf, const float* __restrict__ ssum,
    const __half* __restrict__ xl, float* __restrict__ g) {
    int gid = blockIdx.x * 256 + threadIdx.x;
    if (gid >= kET * kH) return;
    int e = gid >> 2, hh = gid & 3;
    int si = (e < kNE) ? src[e] : e - kNE;
    int di = (e < kNE) ? dst[e] : e - kNE;
    float alpha = __half2float(exbuf[gid]) / ssum[di * kH + hh];
    const __half* pl = xl + (long)si * kHC + hh * kC;
    float* pg = g + (long)di * kHC + hh * kC;
    for (int c = 0; c < kC; ++c) atomicAdd(&pg[c], alpha * __half2float(pl[c]));
}

// ---- K5: global sum / sumsq of (g + gat_b) for PyG graph-mode LayerNorm. LDS tree.
__global__ void __launch_bounds__(256) k_stats(
    const float* __restrict__ g, const float* __restrict__ gat_b, float* __restrict__ stats) {
    __shared__ float rs[256], rq[256];
    int t = threadIdx.x;
    float s = 0.f, q = 0.f;
    long total = (long)kNodes * kHC;
    for (long i = (long)blockIdx.x * 256 + t; i < total; i += (long)gridDim.x * 256) {
        float v = g[i] + gat_b[(int)(i & (kHC - 1))];
        s += v; q += v * v;
    }
    rs[t] = s; rq[t] = q;
    __syncthreads();
    for (int o = 128; o > 0; o >>= 1) {
        if (t < o) { rs[t] += rs[t + o]; rq[t] += rq[t + o]; }
        __syncthreads();
    }
    if (t == 0) {
        atomicAdd(&stats[0], rs[0]);
        atomicAdd(&stats[1], rq[0]);
    }
}

// ---- K6: h = relu(node_ln(relu(graph_ln(g+gat_b)) @ lin_w + lin_b)); jk = max(jk, h)
// block = 256 threads = 2 nodes x 128 features; staging via LDS.
__global__ void __launch_bounds__(256) k_post(
    const float* __restrict__ g, const float* __restrict__ gat_b,
    const float* __restrict__ ln1w, const float* __restrict__ ln1b,
    const float* __restrict__ linw, const float* __restrict__ linb,
    const float* __restrict__ ln2w, const float* __restrict__ ln2b,
    const float* __restrict__ stats, float* __restrict__ h, float* __restrict__ jk) {
    __shared__ float vb[2][kHC];
    __shared__ float yy[2][33];
    int t = threadIdx.x;
    int ng = t >> 7;               // 0..1
    int f  = t & 127;
    int node = blockIdx.x * 2 + ng;
    const float inv = 1.f / ((float)kNodes * kHC);
    float mean = stats[0] * inv;
    float var  = stats[1] * inv - mean * mean;
    float rstd = rsqrtf(var + kEps);
    if (node < kNodes) {
        float a = (g[(long)node * kHC + f] + gat_b[f] - mean) * rstd * ln1w[f] + ln1b[f];
        vb[ng][f] = fmaxf(a, 0.f);
    }
    __syncthreads();
    if (node < kNodes && f < kC) {
        float acc = linb[f];
        for (int k = 0; k < kHC; ++k) acc += vb[ng][k] * linw[k * kC + f];
        yy[ng][f] = acc;
    }
    __syncthreads();
    if (node >= kNodes || f >= kC) return;
    float m = 0.f;
    for (int j = 0; j < kC; ++j) m += yy[ng][j];
    m *= (1.f / kC);
    float q = 0.f;
    for (int j = 0; j < kC; ++j) { float d = yy[ng][j] - m; q += d * d; }
    q *= (1.f / kC);
    float out = (yy[ng][f] - m) * rsqrtf(q + kEps) * ln2w[f] + ln2b[f];
    out = fmaxf(out, 0.f);
    h[node * kC + f] = out;
    jk[node * kC + f] = fmaxf(jk[node * kC + f], out);
}

// ---- K7: fp32 output copy (reference output dtype is float32)
__global__ void __launch_bounds__(256) k_out(const float* __restrict__ jk, float* __restrict__ out) {
    int i = blockIdx.x * 256 + threadIdx.x;
    if (i < kNodes * kC) out[i] = jk[i];
}

extern "C" void kernel_launch(void* const* d_in, const int* in_sizes, int n_in,
                              void* d_out, int out_size, void* d_ws, size_t ws_size,
                              hipStream_t stream) {
    (void)in_sizes; (void)n_in; (void)out_size; (void)ws_size;
    const float* x     = (const float*)d_in[0];
    const int*   ei    = (const int*)d_in[1];
    const int*   src   = ei;
    const int*   dst   = ei + kNE;
    const float* ea    = (const float*)d_in[2];
    const float* W_emb = (const float*)d_in[3];
    const float* b_emb = (const float*)d_in[4];
    const float* ln0w  = (const float*)d_in[5];
    const float* ln0b  = (const float*)d_in[6];
    const float* Wl    = (const float*)d_in[7];
    const float* bl    = (const float*)d_in[8];
    const float* Wr    = (const float*)d_in[9];
    const float* br    = (const float*)d_in[10];
    const float* We    = (const float*)d_in[11];
    const float* att   = (const float*)d_in[12];
    const float* gat_b = (const float*)d_in[13];
    const float* ln1w  = (const float*)d_in[14];
    const float* ln1b  = (const float*)d_in[15];
    const float* linw  = (const float*)d_in[16];
    const float* linb  = (const float*)d_in[17];
    const float* ln2w  = (const float*)d_in[18];
    const float* ln2b  = (const float*)d_in[19];

    // compact workspace: 58.8 MB total.
    // xr aliases g: xr is dead after k_logits; g zero-fill runs after k_logits.
    char* wsb = (char*)d_ws;
    float*  h     = (float*)(wsb);                       // 1.6M fl @ 0
    float*  jk    = (float*)(wsb + 6400000);             // 1.6M fl @ 6.4MB
    float*  xrg   = (float*)(wsb + 12800000);            // 6.4M fl @ 12.8MB (xr, later g)
    __half* xl    = (__half*)(wsb + 38400000);           // 6.4M h  @ 38.4MB
    __half* exbuf = (__half*)(wsb + 51200000);           // 3.4M h  @ 51.2MB
    float*  ssum  = (float*)(wsb + 58000000);            // 200k fl @ 58.0MB
    float*  stats = (float*)(wsb + 58800000);            // 2 fl    @ 58.8MB

    const int smallN = kNodes * kH;            // ssum
    const int gN     = kNodes * kHC;           // g region
    const int embedBlocks = (kNodes + 7) / 8;
    const int transBlocks = (kNodes * kHC + 255) / 256;
    const int edgeBlocks  = (kET * kH + 255) / 256;
    const int postBlocks  = (kNodes + 1) / 2;

    hipLaunchKernelGGL(k_embed, dim3(embedBlocks), dim3(256), 0, stream,
                       x, W_emb, b_emb, ln0w, ln0b, h, jk);
    for (int l = 0; l < 2; ++l) {
        hipLaunchKernelGGL(k_fill0, dim3((smallN + 255) / 256), dim3(256), 0, stream,
                           (unsigned*)ssum, smallN);
        hipLaunchKernelGGL(k_fill0, dim3(1), dim3(256), 0, stream,
                           (unsigned*)stats, 2);
        hipLaunchKernelGGL(k_trans, dim3(transBlocks), dim3(256), 0, stream,
                           h, Wl + l * kC * kHC, bl + l * kHC,
                           Wr + l * kC * kHC, br + l * kHC, xl, xrg);
        hipLaunchKernelGGL(k_logits, dim3(edgeBlocks), dim3(256), 0, stream,
                           src, dst, ea, xl, xrg, We + l * kHC, att + l * kH * kC, exbuf, ssum);
        hipLaunchKernelGGL(k_fill0, dim3((gN + 255) / 256), dim3(256), 0, stream,
                           (unsigned*)xrg, gN);   // xr -> g
        hipLaunchKernelGGL(k_scatter, dim3(edgeBlocks), dim3(256), 0, stream,
                           src, dst, exbuf, ssum, xl, xrg);
        hipLaunchKernelGGL(k_stats, dim3(1024), dim3(256), 0, stream,
                           xrg, gat_b + l * kHC, stats);
        hipLaunchKernelGGL(k_post, dim3(postBlocks), dim3(256), 0, stream,
                           xrg, gat_b + l * kHC, ln1w + l * kHC, ln1b + l * kHC,
                           linw + l * kHC * kC, linb + l * kC,
                           ln2w + l * kC, ln2b + l * kC, stats, h, jk);
    }
    hipLaunchKernelGGL(k_out, dim3((kNodes * kC + 255) / 256), dim3(256), 0, stream,
                       jk, (float*)d_out);
}

// Round 8
// 965.882 us; speedup vs baseline: 12.6641x; 12.6641x over previous
//
#include <hip/hip_runtime.h>
#include <hip/hip_fp16.h>

constexpr int kNodes = 50000;
constexpr int kNE    = 800000;            // edges before self loops
constexpr int kFin   = 256;
constexpr int kC     = 32;
constexpr int kH     = 4;
constexpr int kHC    = 128;               // kH * kC
constexpr int kCH    = 32;                // edge chunk per block iteration
constexpr float kEps   = 1e-5f;
constexpr float kSlope = 0.2f;
constexpr float kShift = 8.0f;            // softmax-invariant global shift

// ---- zero-fill
__global__ void __launch_bounds__(256) k_fill0(unsigned* __restrict__ p, int n) {
    int i = blockIdx.x * 256 + threadIdx.x;
    if (i < n) p[i] = 0u;
}

// ---- K1: h0 = relu(node_ln(x @ W_emb + b_emb)); jk = h0.
__global__ void __launch_bounds__(256) k_embed(
    const float* __restrict__ x, const float* __restrict__ W, const float* __restrict__ b,
    const float* __restrict__ lnw, const float* __restrict__ lnb,
    float* __restrict__ h, float* __restrict__ jk) {
    int t = threadIdx.x;
    int ng = t >> 5, c = t & 31;
    int node = blockIdx.x * 8 + ng;
    __shared__ float sy[8][33];
    float y = 0.f;
    if (node < kNodes) {
        const float* xp = x + (long)node * kFin;
        float acc = 0.f;
        for (int k = 0; k < kFin; ++k) acc += xp[k] * W[k * kC + c];
        y = acc + b[c];
    }
    sy[ng][c] = y;
    __syncthreads();
    if (node >= kNodes) return;
    float m = 0.f;
    for (int j = 0; j < kC; ++j) m += sy[ng][j];
    m *= (1.f / kC);
    float q = 0.f;
    for (int j = 0; j < kC; ++j) { float d = sy[ng][j] - m; q += d * d; }
    q *= (1.f / kC);
    float out = (y - m) * rsqrtf(q + kEps) * lnw[c] + lnb[c];
    out = fmaxf(out, 0.f);
    h[node * kC + c] = out;
    jk[node * kC + c] = out;
}

// ---- K2: xl = h@Wl + bl (fp16) ; xr = h@Wr + br (fp32).
__global__ void __launch_bounds__(256) k_trans(
    const float* __restrict__ h,
    const float* __restrict__ Wl, const float* __restrict__ bl,
    const float* __restrict__ Wr, const float* __restrict__ br,
    __half* __restrict__ xl, float* __restrict__ xr) {
    int gid = blockIdx.x * 256 + threadIdx.x;
    if (gid >= kNodes * kHC) return;
    int node = gid >> 7, j = gid & 127;
    const float* hp = h + (long)node * kC;
    float al = bl[j], ar = br[j];
    for (int k = 0; k < kC; ++k) {
        float hk = hp[k];
        al += hk * Wl[k * kHC + j];
        ar += hk * Wr[k * kHC + j];
    }
    xl[gid] = __float2half(al);
    xr[gid] = ar;
}

// ---- CSR build: histogram, 3-step exclusive scan, reorder
__global__ void __launch_bounds__(256) k_hist(const int* __restrict__ dst, int* __restrict__ deg) {
    int e = blockIdx.x * 256 + threadIdx.x;
    if (e < kNE) atomicAdd(&deg[dst[e]], 1);
}

__global__ void __launch_bounds__(256) k_scan1(const int* __restrict__ deg,
                                               int* __restrict__ excl, int* __restrict__ bsum) {
    __shared__ int s[256];
    int t = threadIdx.x;
    int i = blockIdx.x * 256 + t;
    int v = (i < kNodes) ? deg[i] : 0;
    s[t] = v;
    __syncthreads();
    for (int o = 1; o < 256; o <<= 1) {
        int tv = (t >= o) ? s[t - o] : 0;
        __syncthreads();
        s[t] += tv;
        __syncthreads();
    }
    if (i < kNodes) excl[i] = s[t] - v;
    if (t == 255) bsum[blockIdx.x] = s[255];
}

__global__ void __launch_bounds__(256) k_scan2(int* __restrict__ bsum, int nb) {
    __shared__ int s[256];
    int t = threadIdx.x;
    int v = (t < nb) ? bsum[t] : 0;
    s[t] = v;
    __syncthreads();
    for (int o = 1; o < 256; o <<= 1) {
        int tv = (t >= o) ? s[t - o] : 0;
        __syncthreads();
        s[t] += tv;
        __syncthreads();
    }
    if (t < nb) bsum[t] = s[t];   // inclusive block sums
}

__global__ void __launch_bounds__(256) k_scan3(int* __restrict__ excl, const int* __restrict__ bsum) {
    int i = blockIdx.x * 256 + threadIdx.x;
    if (i >= kNodes) return;
    if (blockIdx.x > 0) excl[i] += bsum[blockIdx.x - 1];
}

__global__ void __launch_bounds__(256) k_reorder(
    const int* __restrict__ src, const int* __restrict__ dst, const float* __restrict__ ea,
    const int* __restrict__ rowptr, int* __restrict__ cur,
    int* __restrict__ esrc, float* __restrict__ eea) {
    int e = blockIdx.x * 256 + threadIdx.x;
    if (e >= kNE) return;
    int d = dst[e];
    int pos = rowptr[d] + atomicAdd(&cur[d], 1);
    esrc[pos] = src[e];
    eea[pos]  = ea[e];
}

// ---- K3 (fused edge phase): one block per dst node, 128 threads = features.
// Gathers incoming edges (CSR), computes GATv2 logits + softmax + weighted sum
// entirely in LDS/registers. Writes g over xr in place (row-private). No atomics.
__global__ void __launch_bounds__(128) k_edge(
    const int* __restrict__ rowptr, const int* __restrict__ deg,
    const int* __restrict__ esrc, const float* __restrict__ eea,
    const __half* __restrict__ xl, float* __restrict__ xrg,
    const float* __restrict__ We, const float* __restrict__ att) {
    __shared__ float s_xr[kHC], s_We[kHC], s_att[kHC], s_tmp[kHC];
    __shared__ int   s_src[kCH];
    __shared__ float s_ea[kCH];
    __shared__ __half s_xl[kCH][kHC];
    __shared__ float s_ex[kCH][kH];
    int d = blockIdx.x;
    int j = threadIdx.x;
    int h = j >> 5, c = j & 31;
    long rowb = (long)d * kHC;
    s_xr[j]  = xrg[rowb + j];
    s_We[j]  = We[j];
    s_att[j] = att[j];
    float xlo = __half2float(xl[rowb + j]);     // own xl row (self loop)
    // self-loop contribution (ea = 0): own-index reads only, then cross-thread dot
    float zs = xlo + s_xr[j];
    zs = (zs > 0.f) ? zs : kSlope * zs;
    s_tmp[j] = zs * s_att[j];
    __syncthreads();                            // s_xr/s_We/s_att/s_tmp now visible
    float lg = 0.f;
    for (int k = 0; k < kC; ++k) lg += s_tmp[h * kC + k];
    float l = expf(lg - kShift);
    float o = l * xlo;

    int base = rowptr[d], cnt = deg[d];
    for (int eoff = 0; eoff < cnt; eoff += kCH) {
        int rem = cnt - eoff;
        int cc = rem < kCH ? rem : kCH;
        __syncthreads();                        // prev iteration's reads done
        if (j < kCH) {
            if (j < cc) { s_src[j] = esrc[base + eoff + j]; s_ea[j] = eea[base + eoff + j]; }
            else        { s_src[j] = 0;                      s_ea[j] = 0.f; }
        }
        __syncthreads();
        for (int e = 0; e < cc; ++e)
            s_xl[e][j] = xl[(long)s_src[e] * kHC + j];
        __syncthreads();
        {   // logits: thread j -> (edge j>>2, head j&3)
            int e = j >> 2, hh = j & 3;
            if (e < cc) {
                float acc = 0.f;
                for (int k = 0; k < kC; ++k) {
                    float z = __half2float(s_xl[e][hh * kC + k]) + s_xr[hh * kC + k]
                              + s_ea[e] * s_We[hh * kC + k];
                    z = (z > 0.f) ? z : kSlope * z;
                    acc += z * s_att[hh * kC + k];
                }
                s_ex[e][hh] = expf(acc - kShift);
            } else {
                s_ex[e][hh] = 0.f;
            }
        }
        __syncthreads();
        for (int e = 0; e < cc; ++e) {
            float ex = s_ex[e][h];
            l += ex;
            o += ex * __half2float(s_xl[e][h * kC + c]);
        }
    }
    xrg[rowb + j] = o / l;                      // g overwrites xr (row-private)
}

// ---- K5: global sum / sumsq of (g + gat_b) for PyG graph-mode LayerNorm.
__global__ void __launch_bounds__(256) k_stats(
    const float* __restrict__ g, const float* __restrict__ gat_b, float* __restrict__ stats) {
    __shared__ float rs[256], rq[256];
    int t = threadIdx.x;
    float s = 0.f, q = 0.f;
    long total = (long)kNodes * kHC;
    for (long i = (long)blockIdx.x * 256 + t; i < total; i += (long)gridDim.x * 256) {
        float v = g[i] + gat_b[(int)(i & (kHC - 1))];
        s += v; q += v * v;
    }
    rs[t] = s; rq[t] = q;
    __syncthreads();
    for (int o = 128; o > 0; o >>= 1) {
        if (t < o) { rs[t] += rs[t + o]; rq[t] += rq[t + o]; }
        __syncthreads();
    }
    if (t == 0) {
        atomicAdd(&stats[0], rs[0]);
        atomicAdd(&stats[1], rq[0]);
    }
}

// ---- K6: h = relu(node_ln(relu(graph_ln(g+gat_b)) @ lin_w + lin_b)); jk = max(jk, h)
__global__ void __launch_bounds__(256) k_post(
    const float* __restrict__ g, const float* __restrict__ gat_b,
    const float* __restrict__ ln1w, const float* __restrict__ ln1b,
    const float* __restrict__ linw, const float* __restrict__ linb,
    const float* __restrict__ ln2w, const float* __restrict__ ln2b,
    const float* __restrict__ stats, float* __restrict__ h, float* __restrict__ jk) {
    __shared__ float vb[2][kHC];
    __shared__ float yy[2][33];
    int t = threadIdx.x;
    int ng = t >> 7, f = t & 127;
    int node = blockIdx.x * 2 + ng;
    const float inv = 1.f / ((float)kNodes * kHC);
    float mean = stats[0] * inv;
    float var  = stats[1] * inv - mean * mean;
    float rstd = rsqrtf(var + kEps);
    if (node < kNodes) {
        float a = (g[(long)node * kHC + f] + gat_b[f] - mean) * rstd * ln1w[f] + ln1b[f];
        vb[ng][f] = fmaxf(a, 0.f);
    }
    __syncthreads();
    if (node < kNodes && f < kC) {
        float acc = linb[f];
        for (int k = 0; k < kHC; ++k) acc += vb[ng][k] * linw[k * kC + f];
        yy[ng][f] = acc;
    }
    __syncthreads();
    if (node >= kNodes || f >= kC) return;
    float m = 0.f;
    for (int j = 0; j < kC; ++j) m += yy[ng][j];
    m *= (1.f / kC);
    float q = 0.f;
    for (int j = 0; j < kC; ++j) { float d = yy[ng][j] - m; q += d * d; }
    q *= (1.f / kC);
    float out = (yy[ng][f] - m) * rsqrtf(q + kEps) * ln2w[f] + ln2b[f];
    out = fmaxf(out, 0.f);
    h[node * kC + f] = out;
    jk[node * kC + f] = fmaxf(jk[node * kC + f], out);
}

// ---- K7: fp32 output copy
__global__ void __launch_bounds__(256) k_out(const float* __restrict__ jk, float* __restrict__ out) {
    int i = blockIdx.x * 256 + threadIdx.x;
    if (i < kNodes * kC) out[i] = jk[i];
}

extern "C" void kernel_launch(void* const* d_in, const int* in_sizes, int n_in,
                              void* d_out, int out_size, void* d_ws, size_t ws_size,
                              hipStream_t stream) {
    (void)in_sizes; (void)n_in; (void)out_size; (void)ws_size;
    const float* x     = (const float*)d_in[0];
    const int*   ei    = (const int*)d_in[1];
    const int*   src   = ei;
    const int*   dst   = ei + kNE;
    const float* ea    = (const float*)d_in[2];
    const float* W_emb = (const float*)d_in[3];
    const float* b_emb = (const float*)d_in[4];
    const float* ln0w  = (const float*)d_in[5];
    const float* ln0b  = (const float*)d_in[6];
    const float* Wl    = (const float*)d_in[7];
    const float* bl    = (const float*)d_in[8];
    const float* Wr    = (const float*)d_in[9];
    const float* br    = (const float*)d_in[10];
    const float* We    = (const float*)d_in[11];
    const float* att   = (const float*)d_in[12];
    const float* gat_b = (const float*)d_in[13];
    const float* ln1w  = (const float*)d_in[14];
    const float* ln1b  = (const float*)d_in[15];
    const float* linw  = (const float*)d_in[16];
    const float* linb  = (const float*)d_in[17];
    const float* ln2w  = (const float*)d_in[18];
    const float* ln2b  = (const float*)d_in[19];

    // workspace layout (bytes). xrg holds xr, overwritten in place by g in k_edge.
    char* wsb = (char*)d_ws;
    float*  h      = (float*)(wsb);                 // 6.4e6 B
    float*  jk     = (float*)(wsb +  6400000);      // 6.4e6 B
    float*  xrg    = (float*)(wsb + 12800000);      // 25.6e6 B
    __half* xl     = (__half*)(wsb + 38400000);     // 12.8e6 B
    int*    esrc   = (int*)(wsb + 51200000);        // 3.2e6 B
    float*  eea    = (float*)(wsb + 54400000);      // 3.2e6 B
    int*    deg    = (int*)(wsb + 57600000);        // 0.2e6 B
    int*    cur    = (int*)(wsb + 57800000);        // 0.2e6 B
    int*    rowptr = (int*)(wsb + 58000000);        // 0.2e6 B
    int*    bsum   = (int*)(wsb + 58200000);        // 1024 B
    float*  stats  = (float*)(wsb + 58201024);      // 8 B
    // end = 58,201,032 bytes (< round-7's proven 58.8 MB)

    const int scanBlocks  = (kNodes + 255) / 256;        // 196
    const int embedBlocks = (kNodes + 7) / 8;
    const int transBlocks = (kNodes * kHC + 255) / 256;
    const int eBlocks     = (kNE + 255) / 256;
    const int postBlocks  = (kNodes + 1) / 2;

    hipLaunchKernelGGL(k_embed, dim3(embedBlocks), dim3(256), 0, stream,
                       x, W_emb, b_emb, ln0w, ln0b, h, jk);
    for (int l = 0; l < 2; ++l) {
        hipLaunchKernelGGL(k_fill0, dim3((2 * kNodes + 255) / 256), dim3(256), 0, stream,
                           (unsigned*)deg, 2 * kNodes);          // deg + cur
        hipLaunchKernelGGL(k_fill0, dim3(1), dim3(256), 0, stream,
                           (unsigned*)stats, 2);
        hipLaunchKernelGGL(k_trans, dim3(transBlocks), dim3(256), 0, stream,
                           h, Wl + l * kC * kHC, bl + l * kHC,
                           Wr + l * kC * kHC, br + l * kHC, xl, xrg);
        hipLaunchKernelGGL(k_hist, dim3(eBlocks), dim3(256), 0, stream, dst, deg);
        hipLaunchKernelGGL(k_scan1, dim3(scanBlocks), dim3(256), 0, stream, deg, rowptr, bsum);
        hipLaunchKernelGGL(k_scan2, dim3(1), dim3(256), 0, stream, bsum, scanBlocks);
        hipLaunchKernelGGL(k_scan3, dim3(scanBlocks), dim3(256), 0, stream, rowptr, bsum);
        hipLaunchKernelGGL(k_reorder, dim3(eBlocks), dim3(256), 0, stream,
                           src, dst, ea, rowptr, cur, esrc, eea);
        hipLaunchKernelGGL(k_edge, dim3(kNodes), dim3(128), 0, stream,
                           rowptr, deg, esrc, eea, xl, xrg,
                           We + l * kHC, att + l * kH * kC);
        hipLaunchKernelGGL(k_stats, dim3(1024), dim3(256), 0, stream,
                           xrg, gat_b + l * kHC, stats);
        hipLaunchKernelGGL(k_post, dim3(postBlocks), dim3(256), 0, stream,
                           xrg, gat_b + l * kHC, ln1w + l * kHC, ln1b + l * kHC,
                           linw + l * kHC * kC, linb + l * kC,
                           ln2w + l * kC, ln2b + l * kC, stats, h, jk);
    }
    hipLaunchKernelGGL(k_out, dim3((kNodes * kC + 255) / 256), dim3(256), 0, stream,
                       jk, (float*)d_out);
}

// Round 9
// 735.675 us; speedup vs baseline: 16.6269x; 1.3129x over previous
//
#include <hip/hip_runtime.h>
#include <hip/hip_fp16.h>

constexpr int kNodes = 50000;
constexpr int kNE    = 800000;            // edges before self loops
constexpr int kFin   = 256;
constexpr int kC     = 32;
constexpr int kH     = 4;
constexpr int kHC    = 128;               // kH * kC
constexpr int kCH    = 32;                // edge chunk per block iteration
constexpr int kPad   = kHC + 8;           // padded LDS row (breaks 256B-stride conflicts)
constexpr float kEps   = 1e-5f;
constexpr float kSlope = 0.2f;
constexpr float kShift = 8.0f;            // softmax-invariant global shift

// ---- zero-fill
__global__ void __launch_bounds__(256) k_fill0(unsigned* __restrict__ p, int n) {
    int i = blockIdx.x * 256 + threadIdx.x;
    if (i < n) p[i] = 0u;
}

// ---- K1: h0 = relu(node_ln(x @ W_emb + b_emb)); jk = h0.
// 8 nodes/block (50000 = 6250*8 exactly). x + W staged in LDS.
__global__ void __launch_bounds__(256) k_embed(
    const float* __restrict__ x, const float* __restrict__ W, const float* __restrict__ b,
    const float* __restrict__ lnw, const float* __restrict__ lnb,
    float* __restrict__ h, float* __restrict__ jk) {
    __shared__ float sx[8 * kFin];        // 8 KB
    __shared__ float sW[kFin * kC];       // 32 KB
    __shared__ float sy[8][33];
    int t = threadIdx.x;
    long base = (long)blockIdx.x * 8 * kFin;
    for (int i = t; i < kFin * kC; i += 256) sW[i] = W[i];
    for (int r = 0; r < 8; ++r) sx[r * 256 + t] = x[base + r * 256 + t];
    __syncthreads();
    int ng = t >> 5, c = t & 31;
    const float* xp = sx + ng * kFin;
    float acc = 0.f;
    #pragma unroll 8
    for (int k = 0; k < kFin; ++k) acc += xp[k] * sW[k * kC + c];
    float y = acc + b[c];
    sy[ng][c] = y;
    __syncthreads();
    float m = 0.f;
    for (int j = 0; j < kC; ++j) m += sy[ng][j];
    m *= (1.f / kC);
    float q = 0.f;
    for (int j = 0; j < kC; ++j) { float d = sy[ng][j] - m; q += d * d; }
    q *= (1.f / kC);
    float out = (y - m) * rsqrtf(q + kEps) * lnw[c] + lnb[c];
    out = fmaxf(out, 0.f);
    int node = blockIdx.x * 8 + ng;
    h[node * kC + c] = out;
    jk[node * kC + c] = out;
}

// ---- K2: xl = h@Wl + bl (fp16) ; xr = h@Wr + br (fp32). 2 nodes/block, h staged.
__global__ void __launch_bounds__(256) k_trans(
    const float* __restrict__ h,
    const float* __restrict__ Wl, const float* __restrict__ bl,
    const float* __restrict__ Wr, const float* __restrict__ br,
    __half* __restrict__ xl, float* __restrict__ xr) {
    __shared__ float sh[64];
    int t = threadIdx.x;
    int ng = t >> 7, j = t & 127;
    int node0 = blockIdx.x * 2;
    if (t < 64) sh[t] = h[node0 * kC + t];
    __syncthreads();
    const float* hp = sh + ng * kC;
    float al = bl[j], ar = br[j];
    #pragma unroll
    for (int k = 0; k < kC; ++k) {
        float hk = hp[k];
        al += hk * Wl[k * kHC + j];
        ar += hk * Wr[k * kHC + j];
    }
    long gid = (long)(node0 + ng) * kHC + j;
    xl[gid] = __float2half(al);
    xr[gid] = ar;
}

// ---- CSR build (dst is layer-invariant: built ONCE)
__global__ void __launch_bounds__(256) k_hist(const int* __restrict__ dst, int* __restrict__ deg) {
    int e = blockIdx.x * 256 + threadIdx.x;
    if (e < kNE) atomicAdd(&deg[dst[e]], 1);
}

__global__ void __launch_bounds__(256) k_scan1(const int* __restrict__ deg,
                                               int* __restrict__ excl, int* __restrict__ bsum) {
    __shared__ int s[256];
    int t = threadIdx.x;
    int i = blockIdx.x * 256 + t;
    int v = (i < kNodes) ? deg[i] : 0;
    s[t] = v;
    __syncthreads();
    for (int o = 1; o < 256; o <<= 1) {
        int tv = (t >= o) ? s[t - o] : 0;
        __syncthreads();
        s[t] += tv;
        __syncthreads();
    }
    if (i < kNodes) excl[i] = s[t] - v;
    if (t == 255) bsum[blockIdx.x] = s[255];
}

__global__ void __launch_bounds__(256) k_scan2(int* __restrict__ bsum, int nb) {
    __shared__ int s[256];
    int t = threadIdx.x;
    int v = (t < nb) ? bsum[t] : 0;
    s[t] = v;
    __syncthreads();
    for (int o = 1; o < 256; o <<= 1) {
        int tv = (t >= o) ? s[t - o] : 0;
        __syncthreads();
        s[t] += tv;
        __syncthreads();
    }
    if (t < nb) bsum[t] = s[t];
}

__global__ void __launch_bounds__(256) k_scan3(int* __restrict__ excl, const int* __restrict__ bsum) {
    int i = blockIdx.x * 256 + threadIdx.x;
    if (i >= kNodes) return;
    if (blockIdx.x > 0) excl[i] += bsum[blockIdx.x - 1];
}

__global__ void __launch_bounds__(256) k_reorder(
    const int* __restrict__ src, const int* __restrict__ dst, const float* __restrict__ ea,
    const int* __restrict__ rowptr, int* __restrict__ cur,
    int* __restrict__ esrc, float* __restrict__ eea) {
    int e = blockIdx.x * 256 + threadIdx.x;
    if (e >= kNE) return;
    int d = dst[e];
    int pos = rowptr[d] + atomicAdd(&cur[d], 1);
    esrc[pos] = src[e];
    eea[pos]  = ea[e];
}

// ---- K3: fused edge phase, one block per dst node. Padded LDS rows (no bank
// conflicts). Epilogue computes per-block graph-LN partial sums (fused k_stats).
__global__ void __launch_bounds__(128) k_edge(
    const int* __restrict__ rowptr, const int* __restrict__ deg,
    const int* __restrict__ esrc, const float* __restrict__ eea,
    const __half* __restrict__ xl, float* __restrict__ xrg,
    const float* __restrict__ We, const float* __restrict__ att,
    const float* __restrict__ gat_b, float* __restrict__ ps, float* __restrict__ pq) {
    __shared__ float s_xr[kHC], s_We[kHC], s_att[kHC], s_tmp[kHC];
    __shared__ int   s_src[kCH];
    __shared__ float s_ea[kCH];
    __shared__ __half s_xl[kCH][kPad];
    __shared__ float s_ex[kCH][kH];
    __shared__ float s_red[4];
    int d = blockIdx.x;
    int j = threadIdx.x;
    int h = j >> 5, c = j & 31;
    long rowb = (long)d * kHC;
    s_xr[j]  = xrg[rowb + j];
    s_We[j]  = We[j];
    s_att[j] = att[j];
    float xlo = __half2float(xl[rowb + j]);     // own xl row (self loop)
    float zs = xlo + s_xr[j];
    zs = (zs > 0.f) ? zs : kSlope * zs;
    s_tmp[j] = zs * s_att[j];
    __syncthreads();
    float lg = 0.f;
    for (int k = 0; k < kC; ++k) lg += s_tmp[h * kC + k];
    float l = expf(lg - kShift);
    float o = l * xlo;

    int base = rowptr[d], cnt = deg[d];
    for (int eoff = 0; eoff < cnt; eoff += kCH) {
        int rem = cnt - eoff;
        int cc = rem < kCH ? rem : kCH;
        __syncthreads();
        if (j < kCH) {
            if (j < cc) { s_src[j] = esrc[base + eoff + j]; s_ea[j] = eea[base + eoff + j]; }
            else        { s_src[j] = 0;                      s_ea[j] = 0.f; }
        }
        __syncthreads();
        for (int e = 0; e < cc; ++e)
            s_xl[e][j] = xl[(long)s_src[e] * kHC + j];
        __syncthreads();
        {   // logits: thread j -> (edge j>>2, head j&3)
            int e = j >> 2, hh = j & 3;
            if (e < cc) {
                float acc = 0.f;
                for (int k = 0; k < kC; ++k) {
                    float z = __half2float(s_xl[e][hh * kC + k]) + s_xr[hh * kC + k]
                              + s_ea[e] * s_We[hh * kC + k];
                    z = (z > 0.f) ? z : kSlope * z;
                    acc += z * s_att[hh * kC + k];
                }
                s_ex[e][hh] = expf(acc - kShift);
            } else {
                s_ex[e][hh] = 0.f;
            }
        }
        __syncthreads();
        for (int e = 0; e < cc; ++e) {
            float ex = s_ex[e][h];
            l += ex;
            o += ex * __half2float(s_xl[e][h * kC + c]);
        }
    }
    float v = o / l;
    xrg[rowb + j] = v;                          // g overwrites xr (row-private)
    // fused graph-LN partials over (v + gat_b)
    float vb = v + gat_b[j];
    float s = vb, q = vb * vb;
    for (int off = 1; off < 64; off <<= 1) { s += __shfl_xor(s, off); q += __shfl_xor(q, off); }
    if ((j & 63) == 0) { s_red[(j >> 6) * 2] = s; s_red[(j >> 6) * 2 + 1] = q; }
    __syncthreads();
    if (j == 0) { ps[d] = s_red[0] + s_red[2]; pq[d] = s_red[1] + s_red[3]; }
}

// ---- K4: reduce per-node partials -> stats[2]. Single block, direct write.
__global__ void __launch_bounds__(1024) k_statsr(
    const float* __restrict__ ps, const float* __restrict__ pq, float* __restrict__ stats) {
    __shared__ float rs[1024], rq[1024];
    int t = threadIdx.x;
    float s = 0.f, q = 0.f;
    for (int i = t; i < kNodes; i += 1024) { s += ps[i]; q += pq[i]; }
    rs[t] = s; rq[t] = q;
    __syncthreads();
    for (int o = 512; o > 0; o >>= 1) {
        if (t < o) { rs[t] += rs[t + o]; rq[t] += rq[t + o]; }
        __syncthreads();
    }
    if (t == 0) { stats[0] = rs[0]; stats[1] = rq[0]; }
}

// ---- K5: h = relu(node_ln(relu(graph_ln(g+gat_b)) @ lin_w + lin_b)); jk_out = max(jk_in, h)
__global__ void __launch_bounds__(256) k_post(
    const float* __restrict__ g, const float* __restrict__ gat_b,
    const float* __restrict__ ln1w, const float* __restrict__ ln1b,
    const float* __restrict__ linw, const float* __restrict__ linb,
    const float* __restrict__ ln2w, const float* __restrict__ ln2b,
    const float* __restrict__ stats, const float* __restrict__ jk_in,
    float* __restrict__ h, float* __restrict__ jk_out) {
    __shared__ float vb[2][kHC];
    __shared__ float yy[2][33];
    int t = threadIdx.x;
    int ng = t >> 7, f = t & 127;
    int node = blockIdx.x * 2 + ng;
    const float inv = 1.f / ((float)kNodes * kHC);
    float mean = stats[0] * inv;
    float var  = stats[1] * inv - mean * mean;
    float rstd = rsqrtf(var + kEps);
    float a = (g[(long)node * kHC + f] + gat_b[f] - mean) * rstd * ln1w[f] + ln1b[f];
    vb[ng][f] = fmaxf(a, 0.f);
    __syncthreads();
    if (f < kC) {
        float acc = linb[f];
        for (int k = 0; k < kHC; ++k) acc += vb[ng][k] * linw[k * kC + f];
        yy[ng][f] = acc;
    }
    __syncthreads();
    if (f >= kC) return;
    float m = 0.f;
    for (int j = 0; j < kC; ++j) m += yy[ng][j];
    m *= (1.f / kC);
    float q = 0.f;
    for (int j = 0; j < kC; ++j) { float d = yy[ng][j] - m; q += d * d; }
    q *= (1.f / kC);
    float out = (yy[ng][f] - m) * rsqrtf(q + kEps) * ln2w[f] + ln2b[f];
    out = fmaxf(out, 0.f);
    h[node * kC + f] = out;
    jk_out[node * kC + f] = fmaxf(jk_in[node * kC + f], out);
}

extern "C" void kernel_launch(void* const* d_in, const int* in_sizes, int n_in,
                              void* d_out, int out_size, void* d_ws, size_t ws_size,
                              hipStream_t stream) {
    (void)in_sizes; (void)n_in; (void)out_size; (void)ws_size;
    const float* x     = (const float*)d_in[0];
    const int*   ei    = (const int*)d_in[1];
    const int*   src   = ei;
    const int*   dst   = ei + kNE;
    const float* ea    = (const float*)d_in[2];
    const float* W_emb = (const float*)d_in[3];
    const float* b_emb = (const float*)d_in[4];
    const float* ln0w  = (const float*)d_in[5];
    const float* ln0b  = (const float*)d_in[6];
    const float* Wl    = (const float*)d_in[7];
    const float* bl    = (const float*)d_in[8];
    const float* Wr    = (const float*)d_in[9];
    const float* br    = (const float*)d_in[10];
    const float* We    = (const float*)d_in[11];
    const float* att   = (const float*)d_in[12];
    const float* gat_b = (const float*)d_in[13];
    const float* ln1w  = (const float*)d_in[14];
    const float* ln1b  = (const float*)d_in[15];
    const float* linw  = (const float*)d_in[16];
    const float* linb  = (const float*)d_in[17];
    const float* ln2w  = (const float*)d_in[18];
    const float* ln2b  = (const float*)d_in[19];

    // workspace layout (bytes). xrg holds xr, overwritten in place by g in k_edge.
    char* wsb = (char*)d_ws;
    float*  h      = (float*)(wsb);                 // 6.4e6 B
    float*  jk     = (float*)(wsb +  6400000);      // 6.4e6 B
    float*  xrg    = (float*)(wsb + 12800000);      // 25.6e6 B
    __half* xl     = (__half*)(wsb + 38400000);     // 12.8e6 B
    int*    esrc   = (int*)(wsb + 51200000);        // 3.2e6 B
    float*  eea    = (float*)(wsb + 54400000);      // 3.2e6 B
    int*    deg    = (int*)(wsb + 57600000);        // 0.2e6 B
    int*    cur    = (int*)(wsb + 57800000);        // 0.2e6 B
    int*    rowptr = (int*)(wsb + 58000000);        // 0.2e6 B
    int*    bsum   = (int*)(wsb + 58200000);        // 1 KB
    float*  stats  = (float*)(wsb + 58201024);      // 8 B
    float*  ps     = (float*)(wsb + 58300000);      // 0.2e6 B
    float*  pq     = (float*)(wsb + 58500000);      // 0.2e6 B
    // end = 58.7e6 bytes (< proven 58.8 MB)

    const int scanBlocks  = (kNodes + 255) / 256;        // 196
    const int embedBlocks = kNodes / 8;                  // 6250 exact
    const int transBlocks = kNodes / 2;                  // 25000 exact
    const int eBlocks     = (kNE + 255) / 256;
    const int postBlocks  = kNodes / 2;                  // 25000 exact

    hipLaunchKernelGGL(k_embed, dim3(embedBlocks), dim3(256), 0, stream,
                       x, W_emb, b_emb, ln0w, ln0b, h, jk);
    // CSR build (once; dst is layer-invariant)
    hipLaunchKernelGGL(k_fill0, dim3((2 * kNodes + 255) / 256), dim3(256), 0, stream,
                       (unsigned*)deg, 2 * kNodes);      // deg + cur
    hipLaunchKernelGGL(k_hist, dim3(eBlocks), dim3(256), 0, stream, dst, deg);
    hipLaunchKernelGGL(k_scan1, dim3(scanBlocks), dim3(256), 0, stream, deg, rowptr, bsum);
    hipLaunchKernelGGL(k_scan2, dim3(1), dim3(256), 0, stream, bsum, scanBlocks);
    hipLaunchKernelGGL(k_scan3, dim3(scanBlocks), dim3(256), 0, stream, rowptr, bsum);
    hipLaunchKernelGGL(k_reorder, dim3(eBlocks), dim3(256), 0, stream,
                       src, dst, ea, rowptr, cur, esrc, eea);
    for (int l = 0; l < 2; ++l) {
        hipLaunchKernelGGL(k_trans, dim3(transBlocks), dim3(256), 0, stream,
                           h, Wl + l * kC * kHC, bl + l * kHC,
                           Wr + l * kC * kHC, br + l * kHC, xl, xrg);
        hipLaunchKernelGGL(k_edge, dim3(kNodes), dim3(128), 0, stream,
                           rowptr, deg, esrc, eea, xl, xrg,
                           We + l * kHC, att + l * kH * kC, gat_b + l * kHC, ps, pq);
        hipLaunchKernelGGL(k_statsr, dim3(1), dim3(1024), 0, stream, ps, pq, stats);
        hipLaunchKernelGGL(k_post, dim3(postBlocks), dim3(256), 0, stream,
                           xrg, gat_b + l * kHC, ln1w + l * kHC, ln1b + l * kHC,
                           linw + l * kHC * kC, linb + l * kC,
                           ln2w + l * kC, ln2b + l * kC, stats, jk,
                           h, (l == 1) ? (float*)d_out : jk);
    }
}

// Round 10
// 634.646 us; speedup vs baseline: 19.2737x; 1.1592x over previous
//
#include <hip/hip_runtime.h>
#include <hip/hip_fp16.h>

constexpr int kNodes = 50000;
constexpr int kNE    = 800000;            // edges before self loops
constexpr int kFin   = 256;
constexpr int kC     = 32;
constexpr int kH     = 4;
constexpr int kHC    = 128;               // kH * kC
constexpr int kCH    = 32;                // edge chunk per block iteration
constexpr float kEps   = 1e-5f;
constexpr float kSlope = 0.2f;
constexpr float kShift = 8.0f;            // softmax-invariant global shift

// ---- zero-fill
__global__ void __launch_bounds__(256) k_fill0(unsigned* __restrict__ p, int n) {
    int i = blockIdx.x * 256 + threadIdx.x;
    if (i < n) p[i] = 0u;
}

// ---- K1: h0 = relu(node_ln(x @ W_emb + b_emb)); jk = h0.  (unchanged from r9)
__global__ void __launch_bounds__(256) k_embed(
    const float* __restrict__ x, const float* __restrict__ W, const float* __restrict__ b,
    const float* __restrict__ lnw, const float* __restrict__ lnb,
    float* __restrict__ h, float* __restrict__ jk) {
    __shared__ float sx[8 * kFin];
    __shared__ float sW[kFin * kC];
    __shared__ float sy[8][33];
    int t = threadIdx.x;
    long base = (long)blockIdx.x * 8 * kFin;
    for (int i = t; i < kFin * kC; i += 256) sW[i] = W[i];
    for (int r = 0; r < 8; ++r) sx[r * 256 + t] = x[base + r * 256 + t];
    __syncthreads();
    int ng = t >> 5, c = t & 31;
    const float* xp = sx + ng * kFin;
    float acc = 0.f;
    #pragma unroll 8
    for (int k = 0; k < kFin; ++k) acc += xp[k] * sW[k * kC + c];
    float y = acc + b[c];
    sy[ng][c] = y;
    __syncthreads();
    float m = 0.f;
    for (int j = 0; j < kC; ++j) m += sy[ng][j];
    m *= (1.f / kC);
    float q = 0.f;
    for (int j = 0; j < kC; ++j) { float d = sy[ng][j] - m; q += d * d; }
    q *= (1.f / kC);
    float out = (y - m) * rsqrtf(q + kEps) * lnw[c] + lnb[c];
    out = fmaxf(out, 0.f);
    int node = blockIdx.x * 8 + ng;
    h[node * kC + c] = out;
    jk[node * kC + c] = out;
}

// ---- K2: xl = h@Wl + bl (fp16) ; xr = h@Wr + br (fp32).
// Wl/Wr columns held in registers; 32 nodes per block staged in LDS.
__global__ void __launch_bounds__(128) k_trans(
    const float* __restrict__ h,
    const float* __restrict__ Wl, const float* __restrict__ bl,
    const float* __restrict__ Wr, const float* __restrict__ br,
    __half* __restrict__ xl, float* __restrict__ xr) {
    __shared__ float s_h[32 * kC];
    int j = threadIdx.x;                  // feature 0..127
    float wl[kC], wr[kC];
    #pragma unroll
    for (int k = 0; k < kC; ++k) { wl[k] = Wl[k * kHC + j]; wr[k] = Wr[k * kHC + j]; }
    float blj = bl[j], brj = br[j];
    int n0 = blockIdx.x * 32;
    int nn = min(32, kNodes - n0);
    for (int i = j; i < nn * kC; i += 128) s_h[i] = h[n0 * kC + i];
    __syncthreads();
    for (int n = 0; n < nn; ++n) {
        const float4* h4 = (const float4*)(s_h + n * kC);
        float al = blj, ar = brj;
        #pragma unroll
        for (int kq = 0; kq < 8; ++kq) {
            float4 hv = h4[kq];
            al += hv.x * wl[kq*4] + hv.y * wl[kq*4+1] + hv.z * wl[kq*4+2] + hv.w * wl[kq*4+3];
            ar += hv.x * wr[kq*4] + hv.y * wr[kq*4+1] + hv.z * wr[kq*4+2] + hv.w * wr[kq*4+3];
        }
        long g = (long)(n0 + n) * kHC + j;
        xl[g] = __float2half(al);
        xr[g] = ar;
    }
}

// ---- CSR build (dst is layer-invariant: built ONCE)
__global__ void __launch_bounds__(256) k_hist(const int* __restrict__ dst, int* __restrict__ deg) {
    int e = blockIdx.x * 256 + threadIdx.x;
    if (e < kNE) atomicAdd(&deg[dst[e]], 1);
}

__global__ void __launch_bounds__(256) k_scan1(const int* __restrict__ deg,
                                               int* __restrict__ excl, int* __restrict__ bsum) {
    __shared__ int s[256];
    int t = threadIdx.x;
    int i = blockIdx.x * 256 + t;
    int v = (i < kNodes) ? deg[i] : 0;
    s[t] = v;
    __syncthreads();
    for (int o = 1; o < 256; o <<= 1) {
        int tv = (t >= o) ? s[t - o] : 0;
        __syncthreads();
        s[t] += tv;
        __syncthreads();
    }
    if (i < kNodes) excl[i] = s[t] - v;
    if (t == 255) bsum[blockIdx.x] = s[255];
}

__global__ void __launch_bounds__(256) k_scan2(int* __restrict__ bsum, int nb) {
    __shared__ int s[256];
    int t = threadIdx.x;
    int v = (t < nb) ? bsum[t] : 0;
    s[t] = v;
    __syncthreads();
    for (int o = 1; o < 256; o <<= 1) {
        int tv = (t >= o) ? s[t - o] : 0;
        __syncthreads();
        s[t] += tv;
        __syncthreads();
    }
    if (t < nb) bsum[t] = s[t];
}

__global__ void __launch_bounds__(256) k_scan3(int* __restrict__ excl, const int* __restrict__ bsum) {
    int i = blockIdx.x * 256 + threadIdx.x;
    if (i >= kNodes) return;
    if (blockIdx.x > 0) excl[i] += bsum[blockIdx.x - 1];
}

__global__ void __launch_bounds__(256) k_reorder(
    const int* __restrict__ src, const int* __restrict__ dst, const float* __restrict__ ea,
    const int* __restrict__ rowptr, int* __restrict__ cur,
    int* __restrict__ esrc, float* __restrict__ eea) {
    int e = blockIdx.x * 256 + threadIdx.x;
    if (e >= kNE) return;
    int d = dst[e];
    int pos = rowptr[d] + atomicAdd(&cur[d], 1);
    esrc[pos] = src[e];
    eea[pos]  = ea[e];
}

// ---- K3: fused edge phase, feature-parallel. Thread j = feature; per edge:
// gather own xl column (register), butterfly-reduce the logit over the 32-lane
// head group, accumulate softmax num/denom in registers. No xl LDS staging.
__global__ void __launch_bounds__(128) k_edge(
    const int* __restrict__ rowptr, const int* __restrict__ deg,
    const int* __restrict__ esrc, const float* __restrict__ eea,
    const __half* __restrict__ xl, float* __restrict__ xrg,
    const float* __restrict__ We, const float* __restrict__ att,
    const float* __restrict__ gat_b, float* __restrict__ ps, float* __restrict__ pq) {
    __shared__ int   s_src[kCH];
    __shared__ float s_ea[kCH];
    __shared__ float s_red[4];
    int d = blockIdx.x;
    int j = threadIdx.x;                  // feature 0..127; head = j>>5
    long rowb = (long)d * kHC;
    float r_xr  = xrg[rowb + j];
    float r_We  = We[j];
    float r_att = att[j];
    float xlo   = __half2float(xl[rowb + j]);

    // self loop (ea = 0)
    float z = xlo + r_xr;
    z = (z > 0.f) ? z : kSlope * z;
    float p = z * r_att;
    #pragma unroll
    for (int mm = 1; mm < 32; mm <<= 1) p += __shfl_xor(p, mm);
    float ex = __expf(p - kShift);
    float l = ex, o = ex * xlo;

    int base = rowptr[d], cnt = deg[d];
    for (int eoff = 0; eoff < cnt; eoff += kCH) {
        int cc = min(kCH, cnt - eoff);
        __syncthreads();
        if (j < cc) { s_src[j] = esrc[base + eoff + j]; s_ea[j] = eea[base + eoff + j]; }
        __syncthreads();
        int e = 0;
        for (; e + 4 <= cc; e += 4) {
            float x0 = __half2float(xl[(long)s_src[e]     * kHC + j]);
            float x1 = __half2float(xl[(long)s_src[e + 1] * kHC + j]);
            float x2 = __half2float(xl[(long)s_src[e + 2] * kHC + j]);
            float x3 = __half2float(xl[(long)s_src[e + 3] * kHC + j]);
            float z0 = x0 + r_xr + s_ea[e]     * r_We; z0 = (z0 > 0.f) ? z0 : kSlope * z0;
            float z1 = x1 + r_xr + s_ea[e + 1] * r_We; z1 = (z1 > 0.f) ? z1 : kSlope * z1;
            float z2 = x2 + r_xr + s_ea[e + 2] * r_We; z2 = (z2 > 0.f) ? z2 : kSlope * z2;
            float z3 = x3 + r_xr + s_ea[e + 3] * r_We; z3 = (z3 > 0.f) ? z3 : kSlope * z3;
            float p0 = z0 * r_att, p1 = z1 * r_att, p2 = z2 * r_att, p3 = z3 * r_att;
            #pragma unroll
            for (int mm = 1; mm < 32; mm <<= 1) {
                p0 += __shfl_xor(p0, mm); p1 += __shfl_xor(p1, mm);
                p2 += __shfl_xor(p2, mm); p3 += __shfl_xor(p3, mm);
            }
            float e0 = __expf(p0 - kShift), e1 = __expf(p1 - kShift);
            float e2 = __expf(p2 - kShift), e3 = __expf(p3 - kShift);
            l += e0 + e1 + e2 + e3;
            o += e0 * x0 + e1 * x1 + e2 * x2 + e3 * x3;
        }
        for (; e < cc; ++e) {
            float xe = __half2float(xl[(long)s_src[e] * kHC + j]);
            float ze = xe + r_xr + s_ea[e] * r_We;
            ze = (ze > 0.f) ? ze : kSlope * ze;
            float pe = ze * r_att;
            #pragma unroll
            for (int mm = 1; mm < 32; mm <<= 1) pe += __shfl_xor(pe, mm);
            float exe = __expf(pe - kShift);
            l += exe;
            o += exe * xe;
        }
    }
    float v = o / l;
    xrg[rowb + j] = v;                    // g overwrites xr (row-private)
    // fused graph-LN partials over (v + gat_b)
    float vb = v + gat_b[j];
    float s = vb, q = vb * vb;
    #pragma unroll
    for (int off = 1; off < 64; off <<= 1) { s += __shfl_xor(s, off); q += __shfl_xor(q, off); }
    if ((j & 63) == 0) { s_red[(j >> 6) * 2] = s; s_red[(j >> 6) * 2 + 1] = q; }
    __syncthreads();
    if (j == 0) { ps[d] = s_red[0] + s_red[2]; pq[d] = s_red[1] + s_red[3]; }
}

// ---- K4: reduce per-node partials -> stats[2].
__global__ void __launch_bounds__(1024) k_statsr(
    const float* __restrict__ ps, const float* __restrict__ pq, float* __restrict__ stats) {
    __shared__ float rs[1024], rq[1024];
    int t = threadIdx.x;
    float s = 0.f, q = 0.f;
    for (int i = t; i < kNodes; i += 1024) { s += ps[i]; q += pq[i]; }
    rs[t] = s; rq[t] = q;
    __syncthreads();
    for (int o = 512; o > 0; o >>= 1) {
        if (t < o) { rs[t] += rs[t + o]; rq[t] += rq[t + o]; }
        __syncthreads();
    }
    if (t == 0) { stats[0] = rs[0]; stats[1] = rq[0]; }
}

// ---- K5: h = relu(node_ln(relu(graph_ln(g+gat_b)) @ lin_w + lin_b)); jk_out = max(jk_in, h)
// 8 nodes/block; linw staged; all 256 threads active in the GEMV; shuffle LN.
__global__ void __launch_bounds__(256) k_post(
    const float* __restrict__ g, const float* __restrict__ gat_b,
    const float* __restrict__ ln1w, const float* __restrict__ ln1b,
    const float* __restrict__ linw, const float* __restrict__ linb,
    const float* __restrict__ ln2w, const float* __restrict__ ln2b,
    const float* __restrict__ stats, const float* __restrict__ jk_in,
    float* __restrict__ h, float* __restrict__ jk_out) {
    __shared__ float s_lw[kHC * kC];      // 16 KB
    __shared__ float s_vb[8 * kHC];       // 4 KB
    int t = threadIdx.x;
    int n0 = blockIdx.x * 8;
    const float inv = 1.f / ((float)kNodes * kHC);
    float mean = stats[0] * inv;
    float var  = stats[1] * inv - mean * mean;
    float rstd = rsqrtf(var + kEps);
    for (int i = t; i < kHC * kC; i += 256) s_lw[i] = linw[i];
    for (int i = t; i < 8 * kHC; i += 256) {
        int node = n0 + (i >> 7), f = i & 127;
        float a = (g[(long)node * kHC + f] + gat_b[f] - mean) * rstd * ln1w[f] + ln1b[f];
        s_vb[i] = fmaxf(a, 0.f);
    }
    __syncthreads();
    int n = t >> 5, c = t & 31;
    int node = n0 + n;
    float acc = linb[c];
    #pragma unroll 8
    for (int k = 0; k < kHC; ++k) acc += s_vb[n * kHC + k] * s_lw[k * kC + c];
    float m = acc;
    #pragma unroll
    for (int mm = 1; mm < 32; mm <<= 1) m += __shfl_xor(m, mm);
    m *= (1.f / kC);
    float dd = acc - m;
    float q = dd * dd;
    #pragma unroll
    for (int mm = 1; mm < 32; mm <<= 1) q += __shfl_xor(q, mm);
    q *= (1.f / kC);
    float out = dd * rsqrtf(q + kEps) * ln2w[c] + ln2b[c];
    out = fmaxf(out, 0.f);
    h[node * kC + c] = out;
    jk_out[node * kC + c] = fmaxf(jk_in[node * kC + c], out);
}

extern "C" void kernel_launch(void* const* d_in, const int* in_sizes, int n_in,
                              void* d_out, int out_size, void* d_ws, size_t ws_size,
                              hipStream_t stream) {
    (void)in_sizes; (void)n_in; (void)out_size; (void)ws_size;
    const float* x     = (const float*)d_in[0];
    const int*   ei    = (const int*)d_in[1];
    const int*   src   = ei;
    const int*   dst   = ei + kNE;
    const float* ea    = (const float*)d_in[2];
    const float* W_emb = (const float*)d_in[3];
    const float* b_emb = (const float*)d_in[4];
    const float* ln0w  = (const float*)d_in[5];
    const float* ln0b  = (const float*)d_in[6];
    const float* Wl    = (const float*)d_in[7];
    const float* bl    = (const float*)d_in[8];
    const float* Wr    = (const float*)d_in[9];
    const float* br    = (const float*)d_in[10];
    const float* We    = (const float*)d_in[11];
    const float* att   = (const float*)d_in[12];
    const float* gat_b = (const float*)d_in[13];
    const float* ln1w  = (const float*)d_in[14];
    const float* ln1b  = (const float*)d_in[15];
    const float* linw  = (const float*)d_in[16];
    const float* linb  = (const float*)d_in[17];
    const float* ln2w  = (const float*)d_in[18];
    const float* ln2b  = (const float*)d_in[19];

    char* wsb = (char*)d_ws;
    float*  h      = (float*)(wsb);                 // 6.4e6 B
    float*  jk     = (float*)(wsb +  6400000);      // 6.4e6 B
    float*  xrg    = (float*)(wsb + 12800000);      // 25.6e6 B (xr, later g)
    __half* xl     = (__half*)(wsb + 38400000);     // 12.8e6 B
    int*    esrc   = (int*)(wsb + 51200000);        // 3.2e6 B
    float*  eea    = (float*)(wsb + 54400000);      // 3.2e6 B
    int*    deg    = (int*)(wsb + 57600000);        // 0.2e6 B
    int*    cur    = (int*)(wsb + 57800000);        // 0.2e6 B
    int*    rowptr = (int*)(wsb + 58000000);        // 0.2e6 B
    int*    bsum   = (int*)(wsb + 58200000);        // 1 KB
    float*  stats  = (float*)(wsb + 58201024);      // 8 B
    float*  ps     = (float*)(wsb + 58300000);      // 0.2e6 B
    float*  pq     = (float*)(wsb + 58500000);      // 0.2e6 B

    const int scanBlocks  = (kNodes + 255) / 256;        // 196
    const int embedBlocks = kNodes / 8;                  // 6250 exact
    const int transBlocks = (kNodes + 31) / 32;          // 1563
    const int eBlocks     = (kNE + 255) / 256;
    const int postBlocks  = kNodes / 8;                  // 6250 exact

    hipLaunchKernelGGL(k_embed, dim3(embedBlocks), dim3(256), 0, stream,
                       x, W_emb, b_emb, ln0w, ln0b, h, jk);
    // CSR build (once; dst is layer-invariant)
    hipLaunchKernelGGL(k_fill0, dim3((2 * kNodes + 255) / 256), dim3(256), 0, stream,
                       (unsigned*)deg, 2 * kNodes);      // deg + cur
    hipLaunchKernelGGL(k_hist, dim3(eBlocks), dim3(256), 0, stream, dst, deg);
    hipLaunchKernelGGL(k_scan1, dim3(scanBlocks), dim3(256), 0, stream, deg, rowptr, bsum);
    hipLaunchKernelGGL(k_scan2, dim3(1), dim3(256), 0, stream, bsum, scanBlocks);
    hipLaunchKernelGGL(k_scan3, dim3(scanBlocks), dim3(256), 0, stream, rowptr, bsum);
    hipLaunchKernelGGL(k_reorder, dim3(eBlocks), dim3(256), 0, stream,
                       src, dst, ea, rowptr, cur, esrc, eea);
    for (int l = 0; l < 2; ++l) {
        hipLaunchKernelGGL(k_trans, dim3(transBlocks), dim3(128), 0, stream,
                           h, Wl + l * kC * kHC, bl + l * kHC,
                           Wr + l * kC * kHC, br + l * kHC, xl, xrg);
        hipLaunchKernelGGL(k_edge, dim3(kNodes), dim3(128), 0, stream,
                           rowptr, deg, esrc, eea, xl, xrg,
                           We + l * kHC, att + l * kH * kC, gat_b + l * kHC, ps, pq);
        hipLaunchKernelGGL(k_statsr, dim3(1), dim3(1024), 0, stream, ps, pq, stats);
        hipLaunchKernelGGL(k_post, dim3(postBlocks), dim3(256), 0, stream,
                           xrg, gat_b + l * kHC, ln1w + l * kHC, ln1b + l * kHC,
                           linw + l * kHC * kC, linb + l * kC,
                           ln2w + l * kC, ln2b + l * kC, stats, jk,
                           h, (l == 1) ? (float*)d_out : jk);
    }
}